// Round 4
// baseline (1846.381 us; speedup 1.0000x reference)
//
#include <hip/hip_runtime.h>
#include <math.h>

#define SEQ    100
#define BATCH  2048
#define DIM    128
#define NF     51
#define NLAYER 2
#define MTOT   (BATCH * NF)
#define BD     (BATCH * DIM)

typedef __attribute__((ext_vector_type(8))) short bf16x8;
typedef __attribute__((ext_vector_type(4))) float f32x4v;

__device__ __forceinline__ unsigned short f2bf(float f) {
    unsigned u = __float_as_uint(f);
    return (unsigned short)((u + 0x7FFFu + ((u >> 16) & 1u)) >> 16);
}

// ---------------------------------------------------------------- tables ---
// imgF [p][k(64)][n(128)] bf16: p0 = 0.1*cos(2pi k n/100), p1 = -0.1*sin; 0-pad.
// imgI [p][n(128)][k(64)] bf16: p0 = a_k*cos, p1 = -a_k*sin; a_k = 0.1/0.2.
__global__ void k_tables(unsigned short* __restrict__ imgF,
                         unsigned short* __restrict__ imgI) {
    const int i = blockIdx.x * 256 + threadIdx.x;   // 16384 per table
    const float W = 6.28318530717958647692f / 100.f;
    if (i < 2 * 64 * 128) {
        const int p = i >> 13, k = (i >> 7) & 63, n = i & 127;
        float v = 0.f;
        if (k < NF && n < SEQ) {
            float s, c; sincosf((float)((k * n) % 100) * W, &s, &c);
            v = 0.1f * (p ? -s : c);
        }
        imgF[i] = f2bf(v);
    }
    if (i < 2 * 128 * 64) {
        const int p = i >> 13, n = (i >> 6) & 127, k = i & 63;
        float v = 0.f;
        if (k < NF && n < SEQ) {
            float s, c; sincosf((float)((k * n) % 100) * W, &s, &c);
            const float a = (k == 0 || k == 50) ? 0.1f : 0.2f;
            v = p ? -a * s : a * c;
        }
        imgI[i] = f2bf(v);
    }
}

// ------------------------------------------ LN + h^T staging (one x pass) --
// h^T LDS: element (c, n) at ushort idx  c*128 + (((n>>3) ^ ((c>>1)&7))<<3) + (n&7)
// Wave wv owns n-chunks {wv, wv+4, wv+8, wv+12}; lane holds c = 2*lane, 2*lane+1.
// Per chunk: 8 float2 loads in flight, 8 full-wave shfl reductions, then two
// conflict-free ds_write_b128 (8 rows packed per c-row).
__device__ __forceinline__ void ln_stage(const float* __restrict__ x,
                                         const float* __restrict__ gamma,
                                         const float* __restrict__ beta,
                                         unsigned short* hT, int b, int t)
{
    const int lane = t & 63, wv = t >> 6;
    const int c0 = lane * 2;
    const float2 gv = *(const float2*)&gamma[c0];
    const float2 bv = *(const float2*)&beta[c0];

    #pragma unroll
    for (int slot = 0; slot < 4; ++slot) {
        const int chunk = slot * 4 + wv;           // 0..15
        const int n0 = chunk * 8;
        float2 v[8];
        #pragma unroll
        for (int j = 0; j < 8; ++j)
            if (n0 + j < SEQ)
                v[j] = *(const float2*)&x[(size_t)(n0 + j) * BD + (size_t)b * DIM + c0];
        unsigned we[4], wo[4];
        #pragma unroll
        for (int j = 0; j < 8; ++j) {
            unsigned short he = 0, ho = 0;
            if (n0 + j < SEQ) {
                float s  = v[j].x + v[j].y;
                float s2 = fmaf(v[j].x, v[j].x, v[j].y * v[j].y);
                #pragma unroll
                for (int off = 1; off < 64; off <<= 1) {
                    s  += __shfl_xor(s,  off, 64);
                    s2 += __shfl_xor(s2, off, 64);
                }
                const float mu   = s * (1.f / 128.f);
                const float rstd = rsqrtf(s2 * (1.f / 128.f) - mu * mu + 1e-5f);
                he = f2bf(fmaf((v[j].x - mu) * rstd, gv.x, bv.x));
                ho = f2bf(fmaf((v[j].y - mu) * rstd, gv.y, bv.y));
            }
            if (j & 1) { we[j >> 1] |= (unsigned)he << 16; wo[j >> 1] |= (unsigned)ho << 16; }
            else       { we[j >> 1]  = he;                 wo[j >> 1]  = ho; }
        }
        const int sw = (chunk ^ (lane & 7)) << 3;   // f(c) = (c>>1)&7 = lane&7
        int4 ve; ve.x = (int)we[0]; ve.y = (int)we[1]; ve.z = (int)we[2]; ve.w = (int)we[3];
        int4 vo; vo.x = (int)wo[0]; vo.y = (int)wo[1]; vo.z = (int)wo[2]; vo.w = (int)wo[3];
        *(int4*)&hT[(c0    ) * 128 + sw] = ve;
        *(int4*)&hT[(c0 + 1) * 128 + sw] = vo;
    }
}

// ------------------------------------------------- A: LN + fwd DFT + normE -
__global__ __launch_bounds__(256, 4) void k_fwd(
    const float* __restrict__ x,
    const float* __restrict__ gamma, const float* __restrict__ beta,
    const unsigned short* __restrict__ imgF,
    float* __restrict__ normE,
    unsigned* __restrict__ hist0)
{
    __shared__ __align__(16) unsigned short hT[128 * 128];   // 32 KB
    __shared__ float epart[64][4];
    __shared__ float energy_s[64];
    __shared__ float med_s;

    const int b = blockIdx.x, t = threadIdx.x;
    const int lane = t & 63, wv = t >> 6, g4 = lane >> 4, cc = lane & 15;

    ln_stage(x, gamma, beta, hT, b, t);
    __syncthreads();

    // B-fragments: wave's 2 c-tiles
    bf16x8 Bf[2][4];
    #pragma unroll
    for (int ct = 0; ct < 2; ++ct) {
        const int c = wv * 32 + ct * 16 + cc;
        #pragma unroll
        for (int ks = 0; ks < 4; ++ks)
            Bf[ct][ks] = *(const bf16x8*)&hT[c * 128 + (((ks * 4 + g4) ^ (cc >> 1)) << 3)];
    }

    #pragma unroll
    for (int mt = 0; mt < 4; ++mt) {
        const int kr = mt * 16 + cc;
        f32x4v aR[2], aI[2];
        aR[0] = aR[1] = aI[0] = aI[1] = (f32x4v){0.f, 0.f, 0.f, 0.f};
        #pragma unroll
        for (int ks = 0; ks < 4; ++ks) {
            const int e0 = kr * 128 + ks * 32 + g4 * 8;
            const bf16x8 A0 = *(const bf16x8*)&imgF[e0];
            const bf16x8 A1 = *(const bf16x8*)&imgF[8192 + e0];
            #pragma unroll
            for (int ct = 0; ct < 2; ++ct) {
                aR[ct] = __builtin_amdgcn_mfma_f32_16x16x32_bf16(A0, Bf[ct][ks], aR[ct], 0, 0, 0);
                aI[ct] = __builtin_amdgcn_mfma_f32_16x16x32_bf16(A1, Bf[ct][ks], aI[ct], 0, 0, 0);
            }
        }
        #pragma unroll
        for (int reg = 0; reg < 4; ++reg) {
            float e = aR[0][reg] * aR[0][reg] + aI[0][reg] * aI[0][reg]
                    + aR[1][reg] * aR[1][reg] + aI[1][reg] * aI[1][reg];
            e += __shfl_xor(e, 1, 64); e += __shfl_xor(e, 2, 64);
            e += __shfl_xor(e, 4, 64); e += __shfl_xor(e, 8, 64);
            if (cc == 0) epart[mt * 16 + g4 * 4 + reg][wv] = e;
        }
    }
    __syncthreads();
    if (t < 64) energy_s[t] = epart[t][0] + epart[t][1] + epart[t][2] + epart[t][3];
    __syncthreads();
    if (t < NF) {
        const float e = energy_s[t];
        int cnt = 0;
        for (int j = 0; j < NF; ++j) {
            const float ej = energy_s[j];
            cnt += (ej < e || (ej == e && j < t)) ? 1 : 0;
        }
        if (cnt == (NF - 1) / 2) med_s = e;
    }
    __syncthreads();
    if (t < NF) {
        const float nE = energy_s[t] / (med_s + 1e-6f);
        normE[b * NF + t] = nE;
        atomicAdd(&hist0[__float_as_uint(nE) >> 21], 1u);   // radix round 0, fused
    }
}

// --------------------------- radix select rounds 1 & 2 (fused hist+scan) ---
// hist layout (u32): [0,2048) round0 | [2048,6144) round1 (2 ranks) |
//                    [6144,8192) round2 (2 ranks)
__global__ void k_sel(const float* __restrict__ normE,
                      unsigned* __restrict__ hist,
                      unsigned* __restrict__ sel,
                      unsigned* __restrict__ done,
                      const float* __restrict__ thrp,
                      const int layer, const int phase,
                      float* __restrict__ thresh)
{
    __shared__ unsigned lh[4096];
    __shared__ unsigned sp[2], sc[2];
    __shared__ unsigned ticket_s;
    __shared__ float vb[2];
    const int t = threadIdx.x;
    const float q = thrp[layer] * (float)(MTOT - 1);
    const unsigned r0 = (unsigned)floorf(q);

    if (phase == 1) {
        // entry scan of round-0 hist (2048 bins, shift 21, shared, prefix 0)
        if (t < 128) {
            const int j = t >> 6, ln = t & 63;
            const unsigned rk = r0 + (unsigned)j;
            unsigned sum = 0;
            for (int i = 0; i < 32; ++i) sum += hist[ln * 32 + i];
            unsigned pre = sum;
            #pragma unroll
            for (int off = 1; off < 64; off <<= 1) {
                const unsigned tt = __shfl_up(pre, off, 64);
                if (ln >= off) pre += tt;
            }
            const unsigned excl = pre - sum;
            if (rk >= excl && rk < excl + sum) {
                unsigned cum = excl;
                for (int i = 0; i < 32; ++i) {
                    const unsigned hc = hist[ln * 32 + i];
                    if (rk < cum + hc) { sp[j] = (unsigned)(ln * 32 + i) << 21; sc[j] = cum; break; }
                    cum += hc;
                }
            }
        }
    } else {
        if (t < 2) { sp[t] = sel[2 * t]; sc[t] = sel[2 * t + 1]; }
    }
    __syncthreads();
    const unsigned p0 = sp[0], p1 = sp[1];
    const int bins      = (phase == 1) ? 2048 : 1024;
    const int shift     = (phase == 1) ? 10 : 0;
    const unsigned hmsk = (phase == 1) ? 0xFFE00000u : 0xFFFFFC00u;
    const int region    = (phase == 1) ? 2048 : 6144;

    for (int i = t; i < 2 * bins; i += 256) lh[i] = 0;
    __syncthreads();
    for (int i = blockIdx.x * 256 + t; i < MTOT; i += gridDim.x * 256) {
        const unsigned v = __float_as_uint(normE[i]);
        const unsigned bin = (v >> shift) & (unsigned)(bins - 1);
        if ((v & hmsk) == p0) atomicAdd(&lh[bin], 1u);
        if ((v & hmsk) == p1) atomicAdd(&lh[bins + bin], 1u);
    }
    __syncthreads();
    for (int i = t; i < 2 * bins; i += 256) {
        const unsigned c = lh[i];
        if (c) atomicAdd(&hist[region + i], c);
    }
    __threadfence();
    if (t == 0) ticket_s = atomicAdd(&done[(layer << 1) + (phase - 1)], 1u);
    __syncthreads();
    if (ticket_s != (unsigned)(gridDim.x - 1)) return;
    __threadfence();

    // last block: scan both ranks of this round
    if (t < 128) {
        const int j = t >> 6, ln = t & 63;
        const unsigned rk  = r0 + (unsigned)j;
        const unsigned rem = rk - sc[j];
        const unsigned* H  = hist + region + j * bins;
        const int per = bins / 64;
        unsigned sum = 0;
        for (int i = 0; i < per; ++i)
            sum += __hip_atomic_load(&H[ln * per + i], __ATOMIC_RELAXED, __HIP_MEMORY_SCOPE_AGENT);
        unsigned pre = sum;
        #pragma unroll
        for (int off = 1; off < 64; off <<= 1) {
            const unsigned tt = __shfl_up(pre, off, 64);
            if (ln >= off) pre += tt;
        }
        const unsigned excl = pre - sum;
        if (rem >= excl && rem < excl + sum) {
            unsigned cum = excl;
            for (int i = 0; i < per; ++i) {
                const unsigned hc = __hip_atomic_load(&H[ln * per + i],
                                        __ATOMIC_RELAXED, __HIP_MEMORY_SCOPE_AGENT);
                if (rem < cum + hc) {
                    const unsigned bin = (unsigned)(ln * per + i);
                    if (phase == 1) { sel[2 * j] = sp[j] | (bin << 10); sel[2 * j + 1] = sc[j] + cum; }
                    else            vb[j] = __uint_as_float(sp[j] | bin);
                    break;
                }
                cum += hc;
            }
        }
    }
    __syncthreads();
    if (phase == 1) { for (int i = t; i < 6144; i += 256) hist[i] = 0u; }
    else            { for (int i = t; i < 2048; i += 256) hist[6144 + i] = 0u; }
    if (t == 0) {
        done[(layer << 1) + (phase - 1)] = 0u;
        if (phase == 2) {
            const float frac = q - floorf(q);
            thresh[0] = vb[0] * (1.f - frac) + vb[1] * frac;
        }
    }
}

// --------------------- C: LN + fwd DFT + weight + inv DFT + residual -------
__global__ __launch_bounds__(256, 4) void k_asb(
    const float* __restrict__ x,
    const float* __restrict__ gamma, const float* __restrict__ beta,
    const float* __restrict__ cw, const float* __restrict__ cwh,
    const unsigned short* __restrict__ imgF,
    const unsigned short* __restrict__ imgI,
    const float* __restrict__ normE, const float* __restrict__ thresh,
    float* __restrict__ out)
{
    __shared__ __align__(16) unsigned short hT[128 * 128];   // h^T, then Y^T in-place
    __shared__ float mask_s[64];

    const int b = blockIdx.x, t = threadIdx.x;
    const int lane = t & 63, wv = t >> 6, g4 = lane >> 4, cc = lane & 15;

    if (t < 64) mask_s[t] = (t < NF && normE[b * NF + t] < thresh[0]) ? 1.f : 0.f;
    ln_stage(x, gamma, beta, hT, b, t);
    __syncthreads();   // the only block-wide barrier

    // fwd B-fragments (own c-rows; after this the rows are reusable by us)
    bf16x8 Bf[2][4];
    #pragma unroll
    for (int ct = 0; ct < 2; ++ct) {
        const int c = wv * 32 + ct * 16 + cc;
        #pragma unroll
        for (int ks = 0; ks < 4; ++ks)
            Bf[ct][ks] = *(const bf16x8*)&hT[c * 128 + (((ks * 4 + g4) ^ (cc >> 1)) << 3)];
    }

    float fwr[2], fwi[2], fhr[2], fhi[2];
    #pragma unroll
    for (int ct = 0; ct < 2; ++ct) {
        const int c = wv * 32 + ct * 16 + cc;
        const float2 w2 = *(const float2*)&cw[2 * c];
        const float2 h2 = *(const float2*)&cwh[2 * c];
        fwr[ct] = w2.x; fwi[ct] = w2.y; fhr[ct] = h2.x; fhi[ct] = h2.y;
    }

    // fwd DFT + weighting; Y^T overwrites this wave's OWN h^T rows.
    // Y(c, plane, k) at ushort idx c*128 + plane*64 + ((chY ^ (cc>>1))<<3) + (k&7)
    #pragma unroll
    for (int mt = 0; mt < 4; ++mt) {
        const int kr = mt * 16 + cc;
        f32x4v aR[2], aI[2];
        aR[0] = aR[1] = aI[0] = aI[1] = (f32x4v){0.f, 0.f, 0.f, 0.f};
        #pragma unroll
        for (int ks = 0; ks < 4; ++ks) {
            const int e0 = kr * 128 + ks * 32 + g4 * 8;
            const bf16x8 A0 = *(const bf16x8*)&imgF[e0];
            const bf16x8 A1 = *(const bf16x8*)&imgF[8192 + e0];
            #pragma unroll
            for (int ct = 0; ct < 2; ++ct) {
                aR[ct] = __builtin_amdgcn_mfma_f32_16x16x32_bf16(A0, Bf[ct][ks], aR[ct], 0, 0, 0);
                aI[ct] = __builtin_amdgcn_mfma_f32_16x16x32_bf16(A1, Bf[ct][ks], aI[ct], 0, 0, 0);
            }
        }
        #pragma unroll
        for (int ct = 0; ct < 2; ++ct) {
            const int c = wv * 32 + ct * 16 + cc;
            unsigned wr[2], wi[2];
            #pragma unroll
            for (int reg = 0; reg < 4; ++reg) {
                const float m   = mask_s[mt * 16 + g4 * 4 + reg];
                const float fre = fmaf(m, fhr[ct], fwr[ct]);
                const float fim = fmaf(m, fhi[ct], fwi[ct]);
                const float xr = aR[ct][reg], xi = aI[ct][reg];
                const unsigned short yr = f2bf(xr * fre - xi * fim);
                const unsigned short yi = f2bf(xr * fim + xi * fre);
                if (reg & 1) { wr[reg >> 1] |= (unsigned)yr << 16; wi[reg >> 1] |= (unsigned)yi << 16; }
                else         { wr[reg >> 1]  = yr;                 wi[reg >> 1]  = yi; }
            }
            const int chY = mt * 2 + (g4 >> 1);
            const int eb  = c * 128 + ((chY ^ (cc >> 1)) << 3) + (g4 & 1) * 4;
            int2 vr; vr.x = (int)wr[0]; vr.y = (int)wr[1];
            int2 vi; vi.x = (int)wi[0]; vi.y = (int)wi[1];
            *(int2*)&hT[eb]      = vr;   // plane 0 (Re)
            *(int2*)&hT[eb + 64] = vi;   // plane 1 (Im)
        }
    }

    // inverse B-fragments from own Y rows
    bf16x8 Yr[2][2], Yi[2][2];
    #pragma unroll
    for (int ct = 0; ct < 2; ++ct) {
        const int c = wv * 32 + ct * 16 + cc;
        #pragma unroll
        for (int kb = 0; kb < 2; ++kb) {
            const int sw = (((kb * 4 + g4) ^ (cc >> 1)) << 3);
            Yr[ct][kb] = *(const bf16x8*)&hT[c * 128 + sw];
            Yi[ct][kb] = *(const bf16x8*)&hT[c * 128 + 64 + sw];
        }
    }

    // inverse DFT + residual + store
    #pragma unroll
    for (int mt = 0; mt < 7; ++mt) {
        const int nr = mt * 16 + cc;
        f32x4v o[2];
        o[0] = o[1] = (f32x4v){0.f, 0.f, 0.f, 0.f};
        #pragma unroll
        for (int kb = 0; kb < 2; ++kb) {
            const int e0 = nr * 64 + kb * 32 + g4 * 8;
            const bf16x8 A0 = *(const bf16x8*)&imgI[e0];
            const bf16x8 A1 = *(const bf16x8*)&imgI[8192 + e0];
            #pragma unroll
            for (int ct = 0; ct < 2; ++ct) {
                o[ct] = __builtin_amdgcn_mfma_f32_16x16x32_bf16(A0, Yr[ct][kb], o[ct], 0, 0, 0);
                o[ct] = __builtin_amdgcn_mfma_f32_16x16x32_bf16(A1, Yi[ct][kb], o[ct], 0, 0, 0);
            }
        }
        #pragma unroll
        for (int ct = 0; ct < 2; ++ct) {
            const int c = wv * 32 + ct * 16 + cc;
            #pragma unroll
            for (int reg = 0; reg < 4; ++reg) {
                const int n = mt * 16 + g4 * 4 + reg;
                if (n < SEQ) {
                    const size_t idx = (size_t)n * BD + (size_t)b * DIM + c;
                    out[idx] = x[idx] + o[ct][reg];
                }
            }
        }
    }
}

// ---------------------------------------------------------------------------
extern "C" void kernel_launch(void* const* d_in, const int* in_sizes, int n_in,
                              void* d_out, int out_size, void* d_ws, size_t ws_size,
                              hipStream_t stream)
{
    (void)in_sizes; (void)n_in; (void)out_size; (void)ws_size;
    const float* x    = (const float*)d_in[0];
    const float* cw   = (const float*)d_in[1];
    const float* cwh  = (const float*)d_in[2];
    const float* thrp = (const float*)d_in[3];
    const float* gam  = (const float*)d_in[4];
    const float* bet  = (const float*)d_in[5];
    float* out = (float*)d_out;

    char* ws = (char*)d_ws;
    unsigned short* imgF = (unsigned short*)(ws);            // 32768 B
    unsigned short* imgI = (unsigned short*)(ws + 32768);    // 32768 B
    float* normE   = (float*)(ws + 65536);                   // 417792 B
    unsigned* hist = (unsigned*)(ws + 483328);               // 32768 B (8192 u32)
    unsigned* done = (unsigned*)(ws + 516096);               // 64 B (4 slots)
    unsigned* sel  = (unsigned*)(ws + 516160);               // 64 B
    float* thresh  = (float*)(ws + 516224);

    k_tables<<<64, 256, 0, stream>>>(imgF, imgI);
    hipMemsetAsync(hist, 0, 32768 + 64, stream);             // hist + done

    for (int l = 0; l < NLAYER; ++l) {
        const float* xi = (l == 0) ? x : out;
        k_fwd<<<BATCH, 256, 0, stream>>>(xi, gam + l * DIM, bet + l * DIM,
                                         imgF, normE, hist);
        k_sel<<<96, 256, 0, stream>>>(normE, hist, sel, done, thrp, l, 1, thresh);
        k_sel<<<96, 256, 0, stream>>>(normE, hist, sel, done, thrp, l, 2, thresh);
        k_asb<<<BATCH, 256, 0, stream>>>(xi, gam + l * DIM, bet + l * DIM,
                                         cw + l * DIM * 2, cwh + l * DIM * 2,
                                         imgF, imgI, normE, thresh, out);
    }
}

// Round 5
// 423.709 us; speedup vs baseline: 4.3577x; 4.3577x over previous
//
#include <hip/hip_runtime.h>
#include <math.h>

#define SEQ    100
#define BATCH  2048
#define DIM    128
#define NF     51
#define NLAYER 2
#define MTOT   (BATCH * NF)
#define BD     (BATCH * DIM)

typedef __attribute__((ext_vector_type(8))) short bf16x8;
typedef __attribute__((ext_vector_type(4))) float f32x4v;

__device__ __forceinline__ unsigned short f2bf(float f) {
    unsigned u = __float_as_uint(f);
    return (unsigned short)((u + 0x7FFFu + ((u >> 16) & 1u)) >> 16);
}

// ---------------------------------------------------------------- tables ---
// imgF [p][k(64)][n(128)] bf16: p0 = 0.1*cos(2pi k n/100), p1 = -0.1*sin; 0-pad.
// imgI [p][n(128)][k(64)] bf16: p0 = a_k*cos, p1 = -a_k*sin; a_k = 0.1/0.2.
__global__ void k_tables(unsigned short* __restrict__ imgF,
                         unsigned short* __restrict__ imgI) {
    const int i = blockIdx.x * 256 + threadIdx.x;   // 16384 per table
    const float W = 6.28318530717958647692f / 100.f;
    if (i < 2 * 64 * 128) {
        const int p = i >> 13, k = (i >> 7) & 63, n = i & 127;
        float v = 0.f;
        if (k < NF && n < SEQ) {
            float s, c; sincosf((float)((k * n) % 100) * W, &s, &c);
            v = 0.1f * (p ? -s : c);
        }
        imgF[i] = f2bf(v);
    }
    if (i < 2 * 128 * 64) {
        const int p = i >> 13, n = (i >> 6) & 127, k = i & 63;
        float v = 0.f;
        if (k < NF && n < SEQ) {
            float s, c; sincosf((float)((k * n) % 100) * W, &s, &c);
            const float a = (k == 0 || k == 50) ? 0.1f : 0.2f;
            v = p ? -a * s : a * c;
        }
        imgI[i] = f2bf(v);
    }
}

// ------------------------------------------ LN + h^T staging (one x pass) --
// h^T LDS: element (c, n) at ushort idx  c*128 + (((n>>3) ^ ((c>>1)&7))<<3) + (n&7)
// Wave wv owns n-chunks {wv, wv+4, wv+8, wv+12}; lane holds c = 2*lane, 2*lane+1.
// Per chunk: 8 float2 loads in flight, 8 full-wave shfl reductions, then two
// conflict-free ds_write_b128 (8 rows packed per c-row).
__device__ __forceinline__ void ln_stage(const float* __restrict__ x,
                                         const float* __restrict__ gamma,
                                         const float* __restrict__ beta,
                                         unsigned short* hT, int b, int t)
{
    const int lane = t & 63, wv = t >> 6;
    const int c0 = lane * 2;
    const float2 gv = *(const float2*)&gamma[c0];
    const float2 bv = *(const float2*)&beta[c0];

    #pragma unroll
    for (int slot = 0; slot < 4; ++slot) {
        const int chunk = slot * 4 + wv;           // 0..15
        const int n0 = chunk * 8;
        float2 v[8];
        #pragma unroll
        for (int j = 0; j < 8; ++j)
            if (n0 + j < SEQ)
                v[j] = *(const float2*)&x[(size_t)(n0 + j) * BD + (size_t)b * DIM + c0];
        unsigned we[4], wo[4];
        #pragma unroll
        for (int j = 0; j < 8; ++j) {
            unsigned short he = 0, ho = 0;
            if (n0 + j < SEQ) {
                float s  = v[j].x + v[j].y;
                float s2 = fmaf(v[j].x, v[j].x, v[j].y * v[j].y);
                #pragma unroll
                for (int off = 1; off < 64; off <<= 1) {
                    s  += __shfl_xor(s,  off, 64);
                    s2 += __shfl_xor(s2, off, 64);
                }
                const float mu   = s * (1.f / 128.f);
                const float rstd = rsqrtf(s2 * (1.f / 128.f) - mu * mu + 1e-5f);
                he = f2bf(fmaf((v[j].x - mu) * rstd, gv.x, bv.x));
                ho = f2bf(fmaf((v[j].y - mu) * rstd, gv.y, bv.y));
            }
            if (j & 1) { we[j >> 1] |= (unsigned)he << 16; wo[j >> 1] |= (unsigned)ho << 16; }
            else       { we[j >> 1]  = he;                 wo[j >> 1]  = ho; }
        }
        const int sw = (chunk ^ (lane & 7)) << 3;   // f(c) = (c>>1)&7 = lane&7
        int4 ve; ve.x = (int)we[0]; ve.y = (int)we[1]; ve.z = (int)we[2]; ve.w = (int)we[3];
        int4 vo; vo.x = (int)wo[0]; vo.y = (int)wo[1]; vo.z = (int)wo[2]; vo.w = (int)wo[3];
        *(int4*)&hT[(c0    ) * 128 + sw] = ve;
        *(int4*)&hT[(c0 + 1) * 128 + sw] = vo;
    }
}

// ------------------------------------------------- A: LN + fwd DFT + normE -
__global__ __launch_bounds__(256, 4) void k_fwd(
    const float* __restrict__ x,
    const float* __restrict__ gamma, const float* __restrict__ beta,
    const unsigned short* __restrict__ imgF,
    float* __restrict__ normE)
{
    __shared__ __align__(16) unsigned short hT[128 * 128];   // 32 KB
    __shared__ float epart[64][4];
    __shared__ float energy_s[64];
    __shared__ float med_s;

    const int b = blockIdx.x, t = threadIdx.x;
    const int lane = t & 63, wv = t >> 6, g4 = lane >> 4, cc = lane & 15;

    ln_stage(x, gamma, beta, hT, b, t);
    __syncthreads();

    // B-fragments: wave's 2 c-tiles
    bf16x8 Bf[2][4];
    #pragma unroll
    for (int ct = 0; ct < 2; ++ct) {
        const int c = wv * 32 + ct * 16 + cc;
        #pragma unroll
        for (int ks = 0; ks < 4; ++ks)
            Bf[ct][ks] = *(const bf16x8*)&hT[c * 128 + (((ks * 4 + g4) ^ (cc >> 1)) << 3)];
    }

    #pragma unroll
    for (int mt = 0; mt < 4; ++mt) {
        const int kr = mt * 16 + cc;
        f32x4v aR[2], aI[2];
        aR[0] = aR[1] = aI[0] = aI[1] = (f32x4v){0.f, 0.f, 0.f, 0.f};
        #pragma unroll
        for (int ks = 0; ks < 4; ++ks) {
            const int e0 = kr * 128 + ks * 32 + g4 * 8;
            const bf16x8 A0 = *(const bf16x8*)&imgF[e0];
            const bf16x8 A1 = *(const bf16x8*)&imgF[8192 + e0];
            #pragma unroll
            for (int ct = 0; ct < 2; ++ct) {
                aR[ct] = __builtin_amdgcn_mfma_f32_16x16x32_bf16(A0, Bf[ct][ks], aR[ct], 0, 0, 0);
                aI[ct] = __builtin_amdgcn_mfma_f32_16x16x32_bf16(A1, Bf[ct][ks], aI[ct], 0, 0, 0);
            }
        }
        #pragma unroll
        for (int reg = 0; reg < 4; ++reg) {
            float e = aR[0][reg] * aR[0][reg] + aI[0][reg] * aI[0][reg]
                    + aR[1][reg] * aR[1][reg] + aI[1][reg] * aI[1][reg];
            e += __shfl_xor(e, 1, 64); e += __shfl_xor(e, 2, 64);
            e += __shfl_xor(e, 4, 64); e += __shfl_xor(e, 8, 64);
            if (cc == 0) epart[mt * 16 + g4 * 4 + reg][wv] = e;
        }
    }
    __syncthreads();
    if (t < 64) energy_s[t] = epart[t][0] + epart[t][1] + epart[t][2] + epart[t][3];
    __syncthreads();
    if (t < NF) {
        const float e = energy_s[t];
        int cnt = 0;
        for (int j = 0; j < NF; ++j) {
            const float ej = energy_s[j];
            cnt += (ej < e || (ej == e && j < t)) ? 1 : 0;
        }
        if (cnt == (NF - 1) / 2) med_s = e;
    }
    __syncthreads();
    if (t < NF) normE[b * NF + t] = energy_s[t] / (med_s + 1e-6f);
}

// ----------------------- radix round 0: LDS-aggregated histogram ----------
__global__ void k_hist0(const float* __restrict__ normE,
                        unsigned* __restrict__ hist)
{
    __shared__ unsigned lh[2048];
    for (int i = threadIdx.x; i < 2048; i += 256) lh[i] = 0;
    __syncthreads();
    for (int i = blockIdx.x * 256 + threadIdx.x; i < MTOT; i += gridDim.x * 256)
        atomicAdd(&lh[__float_as_uint(normE[i]) >> 21], 1u);
    __syncthreads();
    for (int i = threadIdx.x; i < 2048; i += 256) {
        const unsigned c = lh[i];
        if (c) atomicAdd(&hist[i], c);
    }
}

// --------------------------- radix select rounds 1 & 2 (fused hist+scan) ---
// hist layout (u32): [0,2048) round0 | [2048,6144) round1 (2 ranks) |
//                    [6144,8192) round2 (2 ranks)
__global__ void k_sel(const float* __restrict__ normE,
                      unsigned* __restrict__ hist,
                      unsigned* __restrict__ sel,
                      unsigned* __restrict__ done,
                      const float* __restrict__ thrp,
                      const int layer, const int phase,
                      float* __restrict__ thresh)
{
    __shared__ unsigned lh[4096];
    __shared__ unsigned sp[2], sc[2];
    __shared__ unsigned ticket_s;
    __shared__ float vb[2];
    const int t = threadIdx.x;
    const float q = thrp[layer] * (float)(MTOT - 1);
    const unsigned r0 = (unsigned)floorf(q);

    if (phase == 1) {
        // entry scan of round-0 hist (2048 bins, shift 21, prefix 0)
        if (t < 128) {
            const int j = t >> 6, ln = t & 63;
            const unsigned rk = r0 + (unsigned)j;
            unsigned sum = 0;
            for (int i = 0; i < 32; ++i) sum += hist[ln * 32 + i];
            unsigned pre = sum;
            #pragma unroll
            for (int off = 1; off < 64; off <<= 1) {
                const unsigned tt = __shfl_up(pre, off, 64);
                if (ln >= off) pre += tt;
            }
            const unsigned excl = pre - sum;
            if (rk >= excl && rk < excl + sum) {
                unsigned cum = excl;
                for (int i = 0; i < 32; ++i) {
                    const unsigned hc = hist[ln * 32 + i];
                    if (rk < cum + hc) { sp[j] = (unsigned)(ln * 32 + i) << 21; sc[j] = cum; break; }
                    cum += hc;
                }
            }
        }
    } else {
        if (t < 2) { sp[t] = sel[2 * t]; sc[t] = sel[2 * t + 1]; }
    }
    __syncthreads();
    const unsigned p0 = sp[0], p1 = sp[1];
    const int bins      = (phase == 1) ? 2048 : 1024;
    const int shift     = (phase == 1) ? 10 : 0;
    const unsigned hmsk = (phase == 1) ? 0xFFE00000u : 0xFFFFFC00u;
    const int region    = (phase == 1) ? 2048 : 6144;

    for (int i = t; i < 2 * bins; i += 256) lh[i] = 0;
    __syncthreads();
    for (int i = blockIdx.x * 256 + t; i < MTOT; i += gridDim.x * 256) {
        const unsigned v = __float_as_uint(normE[i]);
        const unsigned bin = (v >> shift) & (unsigned)(bins - 1);
        if ((v & hmsk) == p0) atomicAdd(&lh[bin], 1u);
        if ((v & hmsk) == p1) atomicAdd(&lh[bins + bin], 1u);
    }
    __syncthreads();
    for (int i = t; i < 2 * bins; i += 256) {
        const unsigned c = lh[i];
        if (c) atomicAdd(&hist[region + i], c);
    }
    __threadfence();
    if (t == 0) ticket_s = atomicAdd(&done[(layer << 1) + (phase - 1)], 1u);
    __syncthreads();
    if (ticket_s != (unsigned)(gridDim.x - 1)) return;
    __threadfence();

    // last block: scan both ranks of this round
    if (t < 128) {
        const int j = t >> 6, ln = t & 63;
        const unsigned rk  = r0 + (unsigned)j;
        const unsigned rem = rk - sc[j];
        const unsigned* H  = hist + region + j * bins;
        const int per = bins / 64;
        unsigned sum = 0;
        for (int i = 0; i < per; ++i)
            sum += __hip_atomic_load(&H[ln * per + i], __ATOMIC_RELAXED, __HIP_MEMORY_SCOPE_AGENT);
        unsigned pre = sum;
        #pragma unroll
        for (int off = 1; off < 64; off <<= 1) {
            const unsigned tt = __shfl_up(pre, off, 64);
            if (ln >= off) pre += tt;
        }
        const unsigned excl = pre - sum;
        if (rem >= excl && rem < excl + sum) {
            unsigned cum = excl;
            for (int i = 0; i < per; ++i) {
                const unsigned hc = __hip_atomic_load(&H[ln * per + i],
                                        __ATOMIC_RELAXED, __HIP_MEMORY_SCOPE_AGENT);
                if (rem < cum + hc) {
                    const unsigned bin = (unsigned)(ln * per + i);
                    if (phase == 1) { sel[2 * j] = sp[j] | (bin << 10); sel[2 * j + 1] = sc[j] + cum; }
                    else            vb[j] = __uint_as_float(sp[j] | bin);
                    break;
                }
                cum += hc;
            }
        }
    }
    __syncthreads();
    if (phase == 1) { for (int i = t; i < 6144; i += 256) hist[i] = 0u; }
    else            { for (int i = t; i < 2048; i += 256) hist[6144 + i] = 0u; }
    if (t == 0) {
        done[(layer << 1) + (phase - 1)] = 0u;
        if (phase == 2) {
            const float frac = q - floorf(q);
            thresh[0] = vb[0] * (1.f - frac) + vb[1] * frac;
        }
    }
}

// --------------------- C: LN + fwd DFT + weight + inv DFT + residual -------
__global__ __launch_bounds__(256, 4) void k_asb(
    const float* __restrict__ x,
    const float* __restrict__ gamma, const float* __restrict__ beta,
    const float* __restrict__ cw, const float* __restrict__ cwh,
    const unsigned short* __restrict__ imgF,
    const unsigned short* __restrict__ imgI,
    const float* __restrict__ normE, const float* __restrict__ thresh,
    float* __restrict__ out)
{
    __shared__ __align__(16) unsigned short hT[128 * 128];   // h^T, then Y^T in-place
    __shared__ float mask_s[64];

    const int b = blockIdx.x, t = threadIdx.x;
    const int lane = t & 63, wv = t >> 6, g4 = lane >> 4, cc = lane & 15;

    if (t < 64) mask_s[t] = (t < NF && normE[b * NF + t] < thresh[0]) ? 1.f : 0.f;
    ln_stage(x, gamma, beta, hT, b, t);
    __syncthreads();   // the only block-wide barrier

    // fwd B-fragments (own c-rows; after this the rows are reusable by us)
    bf16x8 Bf[2][4];
    #pragma unroll
    for (int ct = 0; ct < 2; ++ct) {
        const int c = wv * 32 + ct * 16 + cc;
        #pragma unroll
        for (int ks = 0; ks < 4; ++ks)
            Bf[ct][ks] = *(const bf16x8*)&hT[c * 128 + (((ks * 4 + g4) ^ (cc >> 1)) << 3)];
    }

    float fwr[2], fwi[2], fhr[2], fhi[2];
    #pragma unroll
    for (int ct = 0; ct < 2; ++ct) {
        const int c = wv * 32 + ct * 16 + cc;
        const float2 w2 = *(const float2*)&cw[2 * c];
        const float2 h2 = *(const float2*)&cwh[2 * c];
        fwr[ct] = w2.x; fwi[ct] = w2.y; fhr[ct] = h2.x; fhi[ct] = h2.y;
    }

    // fwd DFT + weighting; Y^T overwrites this wave's OWN h^T rows.
    // Y(c, plane, k) at ushort idx c*128 + plane*64 + ((chY ^ (cc>>1))<<3) + (k&7)
    #pragma unroll
    for (int mt = 0; mt < 4; ++mt) {
        const int kr = mt * 16 + cc;
        f32x4v aR[2], aI[2];
        aR[0] = aR[1] = aI[0] = aI[1] = (f32x4v){0.f, 0.f, 0.f, 0.f};
        #pragma unroll
        for (int ks = 0; ks < 4; ++ks) {
            const int e0 = kr * 128 + ks * 32 + g4 * 8;
            const bf16x8 A0 = *(const bf16x8*)&imgF[e0];
            const bf16x8 A1 = *(const bf16x8*)&imgF[8192 + e0];
            #pragma unroll
            for (int ct = 0; ct < 2; ++ct) {
                aR[ct] = __builtin_amdgcn_mfma_f32_16x16x32_bf16(A0, Bf[ct][ks], aR[ct], 0, 0, 0);
                aI[ct] = __builtin_amdgcn_mfma_f32_16x16x32_bf16(A1, Bf[ct][ks], aI[ct], 0, 0, 0);
            }
        }
        #pragma unroll
        for (int ct = 0; ct < 2; ++ct) {
            const int c = wv * 32 + ct * 16 + cc;
            unsigned wr[2], wi[2];
            #pragma unroll
            for (int reg = 0; reg < 4; ++reg) {
                const float m   = mask_s[mt * 16 + g4 * 4 + reg];
                const float fre = fmaf(m, fhr[ct], fwr[ct]);
                const float fim = fmaf(m, fhi[ct], fwi[ct]);
                const float xr = aR[ct][reg], xi = aI[ct][reg];
                const unsigned short yr = f2bf(xr * fre - xi * fim);
                const unsigned short yi = f2bf(xr * fim + xi * fre);
                if (reg & 1) { wr[reg >> 1] |= (unsigned)yr << 16; wi[reg >> 1] |= (unsigned)yi << 16; }
                else         { wr[reg >> 1]  = yr;                 wi[reg >> 1]  = yi; }
            }
            const int chY = mt * 2 + (g4 >> 1);
            const int eb  = c * 128 + ((chY ^ (cc >> 1)) << 3) + (g4 & 1) * 4;
            int2 vr; vr.x = (int)wr[0]; vr.y = (int)wr[1];
            int2 vi; vi.x = (int)wi[0]; vi.y = (int)wi[1];
            *(int2*)&hT[eb]      = vr;   // plane 0 (Re)
            *(int2*)&hT[eb + 64] = vi;   // plane 1 (Im)
        }
    }

    // inverse B-fragments from own Y rows
    bf16x8 Yr[2][2], Yi[2][2];
    #pragma unroll
    for (int ct = 0; ct < 2; ++ct) {
        const int c = wv * 32 + ct * 16 + cc;
        #pragma unroll
        for (int kb = 0; kb < 2; ++kb) {
            const int sw = (((kb * 4 + g4) ^ (cc >> 1)) << 3);
            Yr[ct][kb] = *(const bf16x8*)&hT[c * 128 + sw];
            Yi[ct][kb] = *(const bf16x8*)&hT[c * 128 + 64 + sw];
        }
    }

    // inverse DFT + residual + store
    #pragma unroll
    for (int mt = 0; mt < 7; ++mt) {
        const int nr = mt * 16 + cc;
        f32x4v o[2];
        o[0] = o[1] = (f32x4v){0.f, 0.f, 0.f, 0.f};
        #pragma unroll
        for (int kb = 0; kb < 2; ++kb) {
            const int e0 = nr * 64 + kb * 32 + g4 * 8;
            const bf16x8 A0 = *(const bf16x8*)&imgI[e0];
            const bf16x8 A1 = *(const bf16x8*)&imgI[8192 + e0];
            #pragma unroll
            for (int ct = 0; ct < 2; ++ct) {
                o[ct] = __builtin_amdgcn_mfma_f32_16x16x32_bf16(A0, Yr[ct][kb], o[ct], 0, 0, 0);
                o[ct] = __builtin_amdgcn_mfma_f32_16x16x32_bf16(A1, Yi[ct][kb], o[ct], 0, 0, 0);
            }
        }
        #pragma unroll
        for (int ct = 0; ct < 2; ++ct) {
            const int c = wv * 32 + ct * 16 + cc;
            #pragma unroll
            for (int reg = 0; reg < 4; ++reg) {
                const int n = mt * 16 + g4 * 4 + reg;
                if (n < SEQ) {
                    const size_t idx = (size_t)n * BD + (size_t)b * DIM + c;
                    out[idx] = x[idx] + o[ct][reg];
                }
            }
        }
    }
}

// ---------------------------------------------------------------------------
extern "C" void kernel_launch(void* const* d_in, const int* in_sizes, int n_in,
                              void* d_out, int out_size, void* d_ws, size_t ws_size,
                              hipStream_t stream)
{
    (void)in_sizes; (void)n_in; (void)out_size; (void)ws_size;
    const float* x    = (const float*)d_in[0];
    const float* cw   = (const float*)d_in[1];
    const float* cwh  = (const float*)d_in[2];
    const float* thrp = (const float*)d_in[3];
    const float* gam  = (const float*)d_in[4];
    const float* bet  = (const float*)d_in[5];
    float* out = (float*)d_out;

    char* ws = (char*)d_ws;
    unsigned short* imgF = (unsigned short*)(ws);            // 32768 B
    unsigned short* imgI = (unsigned short*)(ws + 32768);    // 32768 B
    float* normE   = (float*)(ws + 65536);                   // 417792 B
    unsigned* hist = (unsigned*)(ws + 483328);               // 32768 B (8192 u32)
    unsigned* done = (unsigned*)(ws + 516096);               // 64 B (4 slots)
    unsigned* sel  = (unsigned*)(ws + 516160);               // 64 B
    float* thresh  = (float*)(ws + 516224);

    k_tables<<<64, 256, 0, stream>>>(imgF, imgI);
    hipMemsetAsync(hist, 0, 32768 + 64, stream);             // hist + done

    for (int l = 0; l < NLAYER; ++l) {
        const float* xi = (l == 0) ? x : out;
        k_fwd<<<BATCH, 256, 0, stream>>>(xi, gam + l * DIM, bet + l * DIM,
                                         imgF, normE);
        k_hist0<<<96, 256, 0, stream>>>(normE, hist);
        k_sel<<<96, 256, 0, stream>>>(normE, hist, sel, done, thrp, l, 1, thresh);
        k_sel<<<96, 256, 0, stream>>>(normE, hist, sel, done, thrp, l, 2, thresh);
        k_asb<<<BATCH, 256, 0, stream>>>(xi, gam + l * DIM, bet + l * DIM,
                                         cw + l * DIM * 2, cwh + l * DIM * 2,
                                         imgF, imgI, normE, thresh, out);
    }
}

// Round 6
// 351.592 us; speedup vs baseline: 5.2515x; 1.2051x over previous
//
#include <hip/hip_runtime.h>
#include <math.h>

#define SEQ    100
#define BATCH  2048
#define DIM    128
#define NF     51
#define NLAYER 2
#define MTOT   (BATCH * NF)
#define BD     (BATCH * DIM)
#define XSTR   16384   // ushorts per batch in Xg: [c(128)][plane(2)][k(64)]

typedef __attribute__((ext_vector_type(8))) short bf16x8;
typedef __attribute__((ext_vector_type(4))) float f32x4v;

__device__ __forceinline__ unsigned short f2bf(float f) {
    unsigned u = __float_as_uint(f);
    return (unsigned short)((u + 0x7FFFu + ((u >> 16) & 1u)) >> 16);
}
__device__ __forceinline__ float bf2f(unsigned short u) {
    return __uint_as_float((unsigned)u << 16);
}

// ---------------------------------------------------------------- tables ---
// imgF [p][k(64)][n(128)] bf16: p0 = 0.1*cos(2pi k n/100), p1 = -0.1*sin; 0-pad.
// imgI [p][n(128)][k(64)] bf16: p0 = a_k*cos, p1 = -a_k*sin; a_k = 0.1/0.2.
__global__ void k_tables(unsigned short* __restrict__ imgF,
                         unsigned short* __restrict__ imgI) {
    const int i = blockIdx.x * 256 + threadIdx.x;   // 16384 per table
    const float W = 6.28318530717958647692f / 100.f;
    if (i < 2 * 64 * 128) {
        const int p = i >> 13, k = (i >> 7) & 63, n = i & 127;
        float v = 0.f;
        if (k < NF && n < SEQ) {
            float s, c; sincosf((float)((k * n) % 100) * W, &s, &c);
            v = 0.1f * (p ? -s : c);
        }
        imgF[i] = f2bf(v);
    }
    if (i < 2 * 128 * 64) {
        const int p = i >> 13, n = (i >> 6) & 127, k = i & 63;
        float v = 0.f;
        if (k < NF && n < SEQ) {
            float s, c; sincosf((float)((k * n) % 100) * W, &s, &c);
            const float a = (k == 0 || k == 50) ? 0.1f : 0.2f;
            v = p ? -a * s : a * c;
        }
        imgI[i] = f2bf(v);
    }
}

// ------------------- A: LN + fwd DFT + X store (bf16) + energy + normE -----
__global__ __launch_bounds__(256, 4) void k_fwd(
    const float* __restrict__ x,
    const float* __restrict__ gamma, const float* __restrict__ beta,
    const unsigned short* __restrict__ imgF,
    unsigned short* __restrict__ Xg,   // [BATCH][c][plane][k64] bf16
    float* __restrict__ normE)
{
    __shared__ __align__(16) unsigned short hT[128 * 128];   // 32 KB
    __shared__ float epart[64][4];
    __shared__ float energy_s[64];
    __shared__ float med_s;

    const int b = blockIdx.x, t = threadIdx.x;
    const int lane = t & 63, wv = t >> 6, g4 = lane >> 4, cc = lane & 15;

    // ---- LN + h^T staging; ALL x loads hoisted (one HBM round-trip) ----
    {
        const int c0 = lane * 2;
        const float2 gv = *(const float2*)&gamma[c0];
        const float2 bv = *(const float2*)&beta[c0];
        float2 v[4][8];
        #pragma unroll
        for (int slot = 0; slot < 4; ++slot) {
            const int n0 = (slot * 4 + wv) * 8;
            #pragma unroll
            for (int j = 0; j < 8; ++j)
                if (n0 + j < SEQ)
                    v[slot][j] = *(const float2*)&x[(size_t)(n0 + j) * BD + (size_t)b * DIM + c0];
        }
        #pragma unroll
        for (int slot = 0; slot < 4; ++slot) {
            const int chunk = slot * 4 + wv;
            const int n0 = chunk * 8;
            unsigned we[4], wo[4];
            #pragma unroll
            for (int j = 0; j < 8; ++j) {
                unsigned short he = 0, ho = 0;
                if (n0 + j < SEQ) {
                    float s  = v[slot][j].x + v[slot][j].y;
                    float s2 = fmaf(v[slot][j].x, v[slot][j].x, v[slot][j].y * v[slot][j].y);
                    #pragma unroll
                    for (int off = 1; off < 64; off <<= 1) {
                        s  += __shfl_xor(s,  off, 64);
                        s2 += __shfl_xor(s2, off, 64);
                    }
                    const float mu   = s * (1.f / 128.f);
                    const float rstd = rsqrtf(s2 * (1.f / 128.f) - mu * mu + 1e-5f);
                    he = f2bf(fmaf((v[slot][j].x - mu) * rstd, gv.x, bv.x));
                    ho = f2bf(fmaf((v[slot][j].y - mu) * rstd, gv.y, bv.y));
                }
                if (j & 1) { we[j >> 1] |= (unsigned)he << 16; wo[j >> 1] |= (unsigned)ho << 16; }
                else       { we[j >> 1]  = he;                 wo[j >> 1]  = ho; }
            }
            const int sw = (chunk ^ (lane & 7)) << 3;   // f(c) = (c>>1)&7 = lane&7
            int4 ve; ve.x = (int)we[0]; ve.y = (int)we[1]; ve.z = (int)we[2]; ve.w = (int)we[3];
            int4 vo; vo.x = (int)wo[0]; vo.y = (int)wo[1]; vo.z = (int)wo[2]; vo.w = (int)wo[3];
            *(int4*)&hT[(c0    ) * 128 + sw] = ve;
            *(int4*)&hT[(c0 + 1) * 128 + sw] = vo;
        }
    }
    __syncthreads();

    // B-fragments: wave's 2 c-tiles
    bf16x8 Bf[2][4];
    #pragma unroll
    for (int ct = 0; ct < 2; ++ct) {
        const int c = wv * 32 + ct * 16 + cc;
        #pragma unroll
        for (int ks = 0; ks < 4; ++ks)
            Bf[ct][ks] = *(const bf16x8*)&hT[c * 128 + (((ks * 4 + g4) ^ (cc >> 1)) << 3)];
    }

    #pragma unroll
    for (int mt = 0; mt < 4; ++mt) {
        const int kr = mt * 16 + cc;
        f32x4v aR[2], aI[2];
        aR[0] = aR[1] = aI[0] = aI[1] = (f32x4v){0.f, 0.f, 0.f, 0.f};
        #pragma unroll
        for (int ks = 0; ks < 4; ++ks) {
            const int e0 = kr * 128 + ks * 32 + g4 * 8;
            const bf16x8 A0 = *(const bf16x8*)&imgF[e0];
            const bf16x8 A1 = *(const bf16x8*)&imgF[8192 + e0];
            #pragma unroll
            for (int ct = 0; ct < 2; ++ct) {
                aR[ct] = __builtin_amdgcn_mfma_f32_16x16x32_bf16(A0, Bf[ct][ks], aR[ct], 0, 0, 0);
                aI[ct] = __builtin_amdgcn_mfma_f32_16x16x32_bf16(A1, Bf[ct][ks], aI[ct], 0, 0, 0);
            }
        }
        // energy partials (f32, before any bf16 rounding)
        #pragma unroll
        for (int reg = 0; reg < 4; ++reg) {
            float e = aR[0][reg] * aR[0][reg] + aI[0][reg] * aI[0][reg]
                    + aR[1][reg] * aR[1][reg] + aI[1][reg] * aI[1][reg];
            e += __shfl_xor(e, 1, 64); e += __shfl_xor(e, 2, 64);
            e += __shfl_xor(e, 4, 64); e += __shfl_xor(e, 8, 64);
            if (cc == 0) epart[mt * 16 + g4 * 4 + reg][wv] = e;
        }
        // X store: acc (k=mt*16+g4*4+reg, c) -> Xg[b][c][plane][k] packed bf16
        #pragma unroll
        for (int ct = 0; ct < 2; ++ct) {
            const int c = wv * 32 + ct * 16 + cc;
            unsigned short* Xb = Xg + (size_t)b * XSTR + (size_t)c * 128;
            const int k0 = mt * 16 + g4 * 4;
            uint2 pr, pi;
            pr.x = (unsigned)f2bf(aR[ct][0]) | ((unsigned)f2bf(aR[ct][1]) << 16);
            pr.y = (unsigned)f2bf(aR[ct][2]) | ((unsigned)f2bf(aR[ct][3]) << 16);
            pi.x = (unsigned)f2bf(aI[ct][0]) | ((unsigned)f2bf(aI[ct][1]) << 16);
            pi.y = (unsigned)f2bf(aI[ct][2]) | ((unsigned)f2bf(aI[ct][3]) << 16);
            *(uint2*)&Xb[k0]      = pr;   // plane 0 (Re)
            *(uint2*)&Xb[64 + k0] = pi;   // plane 1 (Im)
        }
    }
    __syncthreads();
    if (t < 64) energy_s[t] = epart[t][0] + epart[t][1] + epart[t][2] + epart[t][3];
    __syncthreads();
    if (t < NF) {
        const float e = energy_s[t];
        int cnt = 0;
        for (int j = 0; j < NF; ++j) {
            const float ej = energy_s[j];
            cnt += (ej < e || (ej == e && j < t)) ? 1 : 0;
        }
        if (cnt == (NF - 1) / 2) med_s = e;
    }
    __syncthreads();
    if (t < NF) normE[b * NF + t] = energy_s[t] / (med_s + 1e-6f);
}

// ----------------------- radix round 0: LDS-aggregated histogram ----------
__global__ void k_hist0(const float* __restrict__ normE,
                        unsigned* __restrict__ hist)
{
    __shared__ unsigned lh[2048];
    for (int i = threadIdx.x; i < 2048; i += 256) lh[i] = 0;
    __syncthreads();
    for (int i = blockIdx.x * 256 + threadIdx.x; i < MTOT; i += gridDim.x * 256)
        atomicAdd(&lh[__float_as_uint(normE[i]) >> 21], 1u);
    __syncthreads();
    for (int i = threadIdx.x; i < 2048; i += 256) {
        const unsigned c = lh[i];
        if (c) atomicAdd(&hist[i], c);
    }
}

// --------------------------- radix select rounds 1 & 2 (fused hist+scan) ---
// hist layout (u32): [0,2048) round0 | [2048,6144) round1 (2 ranks) |
//                    [6144,8192) round2 (2 ranks)
__global__ void k_sel(const float* __restrict__ normE,
                      unsigned* __restrict__ hist,
                      unsigned* __restrict__ sel,
                      unsigned* __restrict__ done,
                      const float* __restrict__ thrp,
                      const int layer, const int phase,
                      float* __restrict__ thresh)
{
    __shared__ unsigned lh[4096];
    __shared__ unsigned sp[2], sc[2];
    __shared__ unsigned ticket_s;
    __shared__ float vb[2];
    const int t = threadIdx.x;
    const float q = thrp[layer] * (float)(MTOT - 1);
    const unsigned r0 = (unsigned)floorf(q);

    if (phase == 1) {
        if (t < 128) {
            const int j = t >> 6, ln = t & 63;
            const unsigned rk = r0 + (unsigned)j;
            unsigned sum = 0;
            for (int i = 0; i < 32; ++i) sum += hist[ln * 32 + i];
            unsigned pre = sum;
            #pragma unroll
            for (int off = 1; off < 64; off <<= 1) {
                const unsigned tt = __shfl_up(pre, off, 64);
                if (ln >= off) pre += tt;
            }
            const unsigned excl = pre - sum;
            if (rk >= excl && rk < excl + sum) {
                unsigned cum = excl;
                for (int i = 0; i < 32; ++i) {
                    const unsigned hc = hist[ln * 32 + i];
                    if (rk < cum + hc) { sp[j] = (unsigned)(ln * 32 + i) << 21; sc[j] = cum; break; }
                    cum += hc;
                }
            }
        }
    } else {
        if (t < 2) { sp[t] = sel[2 * t]; sc[t] = sel[2 * t + 1]; }
    }
    __syncthreads();
    const unsigned p0 = sp[0], p1 = sp[1];
    const int bins      = (phase == 1) ? 2048 : 1024;
    const int shift     = (phase == 1) ? 10 : 0;
    const unsigned hmsk = (phase == 1) ? 0xFFE00000u : 0xFFFFFC00u;
    const int region    = (phase == 1) ? 2048 : 6144;

    for (int i = t; i < 2 * bins; i += 256) lh[i] = 0;
    __syncthreads();
    for (int i = blockIdx.x * 256 + t; i < MTOT; i += gridDim.x * 256) {
        const unsigned v = __float_as_uint(normE[i]);
        const unsigned bin = (v >> shift) & (unsigned)(bins - 1);
        if ((v & hmsk) == p0) atomicAdd(&lh[bin], 1u);
        if ((v & hmsk) == p1) atomicAdd(&lh[bins + bin], 1u);
    }
    __syncthreads();
    for (int i = t; i < 2 * bins; i += 256) {
        const unsigned c = lh[i];
        if (c) atomicAdd(&hist[region + i], c);
    }
    __threadfence();
    if (t == 0) ticket_s = atomicAdd(&done[(layer << 1) + (phase - 1)], 1u);
    __syncthreads();
    if (ticket_s != (unsigned)(gridDim.x - 1)) return;
    __threadfence();

    if (t < 128) {
        const int j = t >> 6, ln = t & 63;
        const unsigned rk  = r0 + (unsigned)j;
        const unsigned rem = rk - sc[j];
        const unsigned* H  = hist + region + j * bins;
        const int per = bins / 64;
        unsigned sum = 0;
        for (int i = 0; i < per; ++i)
            sum += __hip_atomic_load(&H[ln * per + i], __ATOMIC_RELAXED, __HIP_MEMORY_SCOPE_AGENT);
        unsigned pre = sum;
        #pragma unroll
        for (int off = 1; off < 64; off <<= 1) {
            const unsigned tt = __shfl_up(pre, off, 64);
            if (ln >= off) pre += tt;
        }
        const unsigned excl = pre - sum;
        if (rem >= excl && rem < excl + sum) {
            unsigned cum = excl;
            for (int i = 0; i < per; ++i) {
                const unsigned hc = __hip_atomic_load(&H[ln * per + i],
                                        __ATOMIC_RELAXED, __HIP_MEMORY_SCOPE_AGENT);
                if (rem < cum + hc) {
                    const unsigned bin = (unsigned)(ln * per + i);
                    if (phase == 1) { sel[2 * j] = sp[j] | (bin << 10); sel[2 * j + 1] = sc[j] + cum; }
                    else            vb[j] = __uint_as_float(sp[j] | bin);
                    break;
                }
                cum += hc;
            }
        }
    }
    __syncthreads();
    if (phase == 1) { for (int i = t; i < 6144; i += 256) hist[i] = 0u; }
    else            { for (int i = t; i < 2048; i += 256) hist[6144 + i] = 0u; }
    if (t == 0) {
        done[(layer << 1) + (phase - 1)] = 0u;
        if (phase == 2) {
            const float frac = q - floorf(q);
            thresh[0] = vb[0] * (1.f - frac) + vb[1] * frac;
        }
    }
}

// --------------- C: load X + mask/weight + inv DFT + residual (no LDS) -----
__global__ __launch_bounds__(256, 4) void k_asb(
    const float* __restrict__ x,
    const float* __restrict__ cw, const float* __restrict__ cwh,
    const unsigned short* __restrict__ Xg,
    const unsigned short* __restrict__ imgI,
    const float* __restrict__ normE, const float* __restrict__ thresh,
    float* __restrict__ out)
{
    __shared__ float mask_s[64];

    const int b = blockIdx.x, t = threadIdx.x;
    const int lane = t & 63, wv = t >> 6, g4 = lane >> 4, cc = lane & 15;

    if (t < 64) mask_s[t] = (t < NF && normE[b * NF + t] < thresh[0]) ? 1.f : 0.f;
    __syncthreads();   // the only barrier

    // load X fragments, apply (w + mask*wh) in f32, repack as bf16 B-frags
    bf16x8 Yr[2][2], Yi[2][2];
    #pragma unroll
    for (int ct = 0; ct < 2; ++ct) {
        const int c = wv * 32 + ct * 16 + cc;
        const unsigned short* Xb = Xg + (size_t)b * XSTR + (size_t)c * 128;
        const float2 w2 = *(const float2*)&cw[2 * c];
        const float2 h2 = *(const float2*)&cwh[2 * c];
        #pragma unroll
        for (int kb = 0; kb < 2; ++kb) {
            const bf16x8 xr = *(const bf16x8*)&Xb[kb * 32 + g4 * 8];
            const bf16x8 xi = *(const bf16x8*)&Xb[64 + kb * 32 + g4 * 8];
            bf16x8 yr, yi;
            #pragma unroll
            for (int j = 0; j < 8; ++j) {
                const float m   = mask_s[kb * 32 + g4 * 8 + j];
                const float fre = fmaf(m, h2.x, w2.x);
                const float fim = fmaf(m, h2.y, w2.y);
                const float fxr = bf2f((unsigned short)xr[j]);
                const float fxi = bf2f((unsigned short)xi[j]);
                yr[j] = (short)f2bf(fxr * fre - fxi * fim);
                yi[j] = (short)f2bf(fxr * fim + fxi * fre);
            }
            Yr[ct][kb] = yr; Yi[ct][kb] = yi;
        }
    }

    // inverse DFT + residual + store
    #pragma unroll
    for (int mt = 0; mt < 7; ++mt) {
        const int nr = mt * 16 + cc;
        f32x4v o[2];
        o[0] = o[1] = (f32x4v){0.f, 0.f, 0.f, 0.f};
        #pragma unroll
        for (int kb = 0; kb < 2; ++kb) {
            const int e0 = nr * 64 + kb * 32 + g4 * 8;
            const bf16x8 A0 = *(const bf16x8*)&imgI[e0];
            const bf16x8 A1 = *(const bf16x8*)&imgI[8192 + e0];
            #pragma unroll
            for (int ct = 0; ct < 2; ++ct) {
                o[ct] = __builtin_amdgcn_mfma_f32_16x16x32_bf16(A0, Yr[ct][kb], o[ct], 0, 0, 0);
                o[ct] = __builtin_amdgcn_mfma_f32_16x16x32_bf16(A1, Yi[ct][kb], o[ct], 0, 0, 0);
            }
        }
        #pragma unroll
        for (int ct = 0; ct < 2; ++ct) {
            const int c = wv * 32 + ct * 16 + cc;
            #pragma unroll
            for (int reg = 0; reg < 4; ++reg) {
                const int n = mt * 16 + g4 * 4 + reg;
                if (n < SEQ) {
                    const size_t idx = (size_t)n * BD + (size_t)b * DIM + c;
                    out[idx] = x[idx] + o[ct][reg];
                }
            }
        }
    }
}

// ---------------------------------------------------------------------------
extern "C" void kernel_launch(void* const* d_in, const int* in_sizes, int n_in,
                              void* d_out, int out_size, void* d_ws, size_t ws_size,
                              hipStream_t stream)
{
    (void)in_sizes; (void)n_in; (void)out_size; (void)ws_size;
    const float* x    = (const float*)d_in[0];
    const float* cw   = (const float*)d_in[1];
    const float* cwh  = (const float*)d_in[2];
    const float* thrp = (const float*)d_in[3];
    const float* gam  = (const float*)d_in[4];
    const float* bet  = (const float*)d_in[5];
    float* out = (float*)d_out;

    char* ws = (char*)d_ws;
    unsigned short* imgF = (unsigned short*)(ws);                    // 32768 B
    unsigned short* imgI = (unsigned short*)(ws + 32768);            // 32768 B
    unsigned short* Xg   = (unsigned short*)(ws + 65536);            // 67,108,864 B
    float* normE   = (float*)(ws + 65536 + 67108864);                // 417,792 B
    unsigned* hist = (unsigned*)(ws + 65536 + 67108864 + 417792);    // 32768 B
    unsigned* done = (unsigned*)(ws + 65536 + 67108864 + 417792 + 32768);        // 64 B
    unsigned* sel  = (unsigned*)(ws + 65536 + 67108864 + 417792 + 32768 + 64);   // 64 B
    float* thresh  = (float*)(ws + 65536 + 67108864 + 417792 + 32768 + 128);

    k_tables<<<64, 256, 0, stream>>>(imgF, imgI);
    hipMemsetAsync(hist, 0, 32768 + 64, stream);   // hist + done

    for (int l = 0; l < NLAYER; ++l) {
        const float* xi = (l == 0) ? x : out;
        k_fwd<<<BATCH, 256, 0, stream>>>(xi, gam + l * DIM, bet + l * DIM,
                                         imgF, Xg, normE);
        k_hist0<<<96, 256, 0, stream>>>(normE, hist);
        k_sel<<<96, 256, 0, stream>>>(normE, hist, sel, done, thrp, l, 1, thresh);
        k_sel<<<96, 256, 0, stream>>>(normE, hist, sel, done, thrp, l, 2, thresh);
        k_asb<<<BATCH, 256, 0, stream>>>(xi, cw + l * DIM * 2, cwh + l * DIM * 2,
                                         Xg, imgI, normE, thresh, out);
    }
}